// Round 12
// baseline (99.135 us; speedup 1.0000x reference)
//
#include <hip/hip_runtime.h>
#include <hip/hip_fp16.h>

#define BB 16
#define NN 4096
#define CC 6
#define NSEG (BB * NN)          // 65536 points per direction-role
#define NTILE 128               // 4096 cols / 32
#define NBLK 1024               // min-kernel blocks

using half8  = __attribute__((ext_vector_type(8))) _Float16;
using f32x16 = __attribute__((ext_vector_type(16))) float;

// ws layout:
//   half8 Af[2][BB][NN] @ 0     (2 MB) A entry per ROW point: (-2h0,-2h1,-2h2,1,1,0,0,0)
//   half8 Bf[2][BB][NN] @ 2 MB  (2 MB) B entry per COL point: ( h0, h1, h2,hi,lo,0,0,0)
//   float rx[2][BB][NN] @ 4 MB  (512 KB) row-point |h|^2 fp32 (absorbs tail over-read)
//   float bpart[NBLK]   @ 4.5MB (4 KB) per-block partials

__global__ __launch_bounds__(256) void chamfer_prep_kernel(
    const float* __restrict__ xg, const float* __restrict__ yg,
    half8* __restrict__ Af, half8* __restrict__ Bf, float* __restrict__ rx)
{
    const int p   = blockIdx.x * 256 + threadIdx.x;   // 0..131071
    const int dir = p >> 16;
    const int rem = p & (NSEG - 1);
    const float* __restrict__ R  = dir ? yg : xg;   // row cloud (min FOR its points)
    const float* __restrict__ Cl = dir ? xg : yg;   // col cloud (min OVER its points)

    {   // row side
        const float c0 = R[(size_t)rem * CC + 0];
        const float c1 = R[(size_t)rem * CC + 1];
        const float c2 = R[(size_t)rem * CC + 2];
        const _Float16 h0 = (_Float16)c0, h1 = (_Float16)c1, h2 = (_Float16)c2;
        const float f0 = (float)h0, f1 = (float)h1, f2 = (float)h2;
        rx[p] = fmaf(f0, f0, fmaf(f1, f1, f2 * f2));
        half8 a = { (_Float16)(-2.0f) * h0, (_Float16)(-2.0f) * h1,
                    (_Float16)(-2.0f) * h2, (_Float16)1.0f, (_Float16)1.0f,
                    (_Float16)0.0f, (_Float16)0.0f, (_Float16)0.0f };
        Af[p] = a;
    }
    {   // col side: ry as hi/lo fp16 pair in K-slots 3,4
        const float c0 = Cl[(size_t)rem * CC + 0];
        const float c1 = Cl[(size_t)rem * CC + 1];
        const float c2 = Cl[(size_t)rem * CC + 2];
        const _Float16 h0 = (_Float16)c0, h1 = (_Float16)c1, h2 = (_Float16)c2;
        const float f0 = (float)h0, f1 = (float)h1, f2 = (float)h2;
        const float r  = fmaf(f0, f0, fmaf(f1, f1, f2 * f2));
        const _Float16 hi = (_Float16)r;
        const _Float16 lo = (_Float16)(r - (float)hi);
        half8 bfr = { h0, h1, h2, hi, lo,
                      (_Float16)0.0f, (_Float16)0.0f, (_Float16)0.0f };
        Bf[p] = bfr;
    }
}

// grid = 1024 blocks x 256 thr (4 waves). wave -> (dir, b, rowgroup of 32); full j-range.
// __launch_bounds__(256, 1): per-wave reg budget 512 (unified VGPR+AGPR) so the
// ~120-reg working set (zc+mn+4 D-tiles+4 B-tiles) fits in arch VGPRs with no
// AGPR shuttling. Allocator should land ~130 regs -> 3 waves/EU naturally.
__global__ __launch_bounds__(256, 1) void chamfer_min_kernel(
    const half8* __restrict__ Af, const half8* __restrict__ Bf,
    const float* __restrict__ rx, float* __restrict__ bpart)
{
    const int bid  = blockIdx.x;
    const int dir  = bid & 1;
    const int b    = (bid >> 1) & 15;
    const int gq   = bid >> 5;                 // 0..31
    const int tid  = threadIdx.x;
    const int w    = tid >> 6;
    const int lane = tid & 63;
    const int l31  = lane & 31;
    const int hf   = lane >> 5;                // K-half select for A (upper = zeros)
    const int g    = gq * 4 + w;               // rowgroup 0..127

    const size_t base = ((size_t)dir << 16) + ((size_t)b << 12);

    half8 a = {};
    if (hf == 0) a = Af[base + (size_t)g * 32 + l31];   // one-time guarded load

    // B loads unguarded: lanes 32..63 feed k=8..15, which A zeroes out.
    const half8* __restrict__ pb = Bf + base + l31;

    const f32x16 zc = {};
    float mn[16];
    #pragma unroll
    for (int s = 0; s < 16; ++s) mn[s] = 3.4e38f;

    half8 b0 = pb[0];
    half8 b1 = pb[32];
    half8 b2 = pb[64];
    half8 b3 = pb[96];
    const half8* pf = pb + 128;

    for (int jt = 0; jt < NTILE; jt += 4) {
        const f32x16 d0 = __builtin_amdgcn_mfma_f32_32x32x16_f16(a, b0, zc, 0, 0, 0);
        const f32x16 d1 = __builtin_amdgcn_mfma_f32_32x32x16_f16(a, b1, zc, 0, 0, 0);
        const half8 n0 = pf[0];                 // prefetch tiles jt+4, jt+5
        const half8 n1 = pf[32];
        #pragma unroll
        for (int s = 0; s < 16; ++s)
            mn[s] = fminf(mn[s], fminf(d0[s], d1[s]));   // -> v_min3_f32

        const f32x16 e0 = __builtin_amdgcn_mfma_f32_32x32x16_f16(a, b2, zc, 0, 0, 0);
        const f32x16 e1 = __builtin_amdgcn_mfma_f32_32x32x16_f16(a, b3, zc, 0, 0, 0);
        const half8 n2 = pf[64];                // prefetch tiles jt+6, jt+7
        const half8 n3 = pf[96];
        #pragma unroll
        for (int s = 0; s < 16; ++s)
            mn[s] = fminf(mn[s], fminf(e0[s], e1[s]));

        b0 = n0; b1 = n1; b2 = n2; b3 = n3;
        pf += 128;
        // final-iter prefetch over-reads <=2KB past Bf into rx region: valid ws
    }

    // cross-lane min over the 32 cols within each half (halves hold different rows)
    #pragma unroll
    for (int s = 0; s < 16; ++s) {
        float v = mn[s];
        v = fminf(v, __shfl_xor(v, 1,  64));
        v = fminf(v, __shfl_xor(v, 2,  64));
        v = fminf(v, __shfl_xor(v, 4,  64));
        v = fminf(v, __shfl_xor(v, 8,  64));
        v = fminf(v, __shfl_xor(v, 16, 64));
        mn[s] = v;
    }

    // add rx per row, sum this half's 16 rows
    const float* __restrict__ rxb = rx + base + (size_t)g * 32;
    float s16 = 0.0f;
    #pragma unroll
    for (int s = 0; s < 16; ++s) {
        const int row = (s & 3) + 8 * (s >> 2) + 4 * hf;  // C/D row map (m101)
        s16 += fmaxf(mn[s] + rxb[row], 0.0f);             // clamp fp noise at 0
    }

    __shared__ float hsum[8];
    if (l31 == 0) hsum[w * 2 + hf] = s16;
    __syncthreads();
    if (tid == 0) {
        float t = 0.0f;
        #pragma unroll
        for (int k = 0; k < 8; ++k) t += hsum[k];
        bpart[bid] = t;            // plain store — no atomics anywhere
    }
}

__global__ __launch_bounds__(256) void chamfer_final_kernel(
    const float* __restrict__ bpart, float* __restrict__ out)
{
    const int tid = threadIdx.x;
    float s = bpart[tid] + bpart[tid + 256] + bpart[tid + 512] + bpart[tid + 768];
    for (int off = 32; off > 0; off >>= 1)
        s += __shfl_down(s, off, 64);
    __shared__ float wsum[4];
    if ((tid & 63) == 0) wsum[tid >> 6] = s;
    __syncthreads();
    if (tid == 0)
        out[0] = (wsum[0] + wsum[1] + wsum[2] + wsum[3]) * (1.0f / NSEG);
}

extern "C" void kernel_launch(void* const* d_in, const int* in_sizes, int n_in,
                              void* d_out, int out_size, void* d_ws, size_t ws_size,
                              hipStream_t stream) {
    const float* x = (const float*)d_in[0];
    const float* y = (const float*)d_in[1];
    float* out = (float*)d_out;

    half8* Af = (half8*)d_ws;
    half8* Bf = (half8*)((char*)d_ws + (size_t)2 * NSEG * sizeof(half8));
    float* rx = (float*)((char*)d_ws + (size_t)4 * NSEG * sizeof(half8));
    float* bpart = (float*)((char*)rx + (size_t)2 * NSEG * sizeof(float));

    chamfer_prep_kernel<<<2 * NSEG / 256, 256, 0, stream>>>(x, y, Af, Bf, rx);
    chamfer_min_kernel<<<NBLK, 256, 0, stream>>>(Af, Bf, rx, bpart);
    chamfer_final_kernel<<<1, 256, 0, stream>>>(bpart, out);
}

// Round 13
// 82.698 us; speedup vs baseline: 1.1988x; 1.1988x over previous
//
#include <hip/hip_runtime.h>
#include <hip/hip_fp16.h>

#define BB 16
#define NN 4096
#define CC 6
#define NSEG (BB * NN)          // 65536 points per direction-role
#define NTILE 128               // 4096 cols / 32
#define NBLK 1024               // min-kernel blocks

using half8  = __attribute__((ext_vector_type(8))) _Float16;

// ---- explicit-register asm inner loop ------------------------------------
// Fixed map: zc v[64:79] | d0 v[80:95] | d1 v[96:111]
//            P tiles v[112:115][116:119][120:123][124:127]
//            Q tiles v[128:131][132:135][136:139][140:143]
//            addrP v[144:145]  addrQ v[146:147]
#define FOLD16 \
  "v_min3_f32 %[m0],  %[m0],  v80, v96\n\t"  \
  "v_min3_f32 %[m1],  %[m1],  v81, v97\n\t"  \
  "v_min3_f32 %[m2],  %[m2],  v82, v98\n\t"  \
  "v_min3_f32 %[m3],  %[m3],  v83, v99\n\t"  \
  "v_min3_f32 %[m4],  %[m4],  v84, v100\n\t" \
  "v_min3_f32 %[m5],  %[m5],  v85, v101\n\t" \
  "v_min3_f32 %[m6],  %[m6],  v86, v102\n\t" \
  "v_min3_f32 %[m7],  %[m7],  v87, v103\n\t" \
  "v_min3_f32 %[m8],  %[m8],  v88, v104\n\t" \
  "v_min3_f32 %[m9],  %[m9],  v89, v105\n\t" \
  "v_min3_f32 %[m10], %[m10], v90, v106\n\t" \
  "v_min3_f32 %[m11], %[m11], v91, v107\n\t" \
  "v_min3_f32 %[m12], %[m12], v92, v108\n\t" \
  "v_min3_f32 %[m13], %[m13], v93, v109\n\t" \
  "v_min3_f32 %[m14], %[m14], v94, v110\n\t" \
  "v_min3_f32 %[m15], %[m15], v95, v111\n\t"

#define PHASE(T0, T1, T2, T3, ALO, AHI, APAIR)                              \
  "s_waitcnt vmcnt(4)\n\t"                                                  \
  "v_mfma_f32_32x32x16_f16 v[80:95],  %[fa], " T0 ", v[64:79]\n\t"          \
  "v_mfma_f32_32x32x16_f16 v[96:111], %[fa], " T1 ", v[64:79]\n\t"          \
  "v_add_co_u32 " ALO ", vcc, 0x1000, " ALO "\n\t"                          \
  "v_addc_co_u32 " AHI ", vcc, 0, " AHI ", vcc\n\t"                         \
  "s_nop 1\n\t"                                                             \
  "global_load_dwordx4 " T0 ", " APAIR ", off\n\t"                          \
  "global_load_dwordx4 " T1 ", " APAIR ", off offset:512\n\t"               \
  "s_nop 7\n\t"                                                             \
  "s_nop 7\n\t"                                                             \
  FOLD16                                                                    \
  "v_mfma_f32_32x32x16_f16 v[80:95],  %[fa], " T2 ", v[64:79]\n\t"          \
  "v_mfma_f32_32x32x16_f16 v[96:111], %[fa], " T3 ", v[64:79]\n\t"          \
  "global_load_dwordx4 " T2 ", " APAIR ", off offset:1024\n\t"              \
  "global_load_dwordx4 " T3 ", " APAIR ", off offset:1536\n\t"              \
  "s_nop 7\n\t"                                                             \
  "s_nop 7\n\t"                                                             \
  "s_nop 4\n\t"                                                             \
  FOLD16

// ws layout:
//   half8 Af[2][BB][NN] @ 0     (2 MB) A entry per ROW point: (-2h0,-2h1,-2h2,1,1,0,0,0)
//   half8 Bf[2][BB][NN] @ 2 MB  (2 MB) B entry per COL point: ( h0, h1, h2,hi,lo,0,0,0)
//   float rx[2][BB][NN] @ 4 MB  (512 KB) row-point |h|^2 fp32 (absorbs tail over-read)
//   float bpart[NBLK]   @ 4.5MB (4 KB) per-block partials

__global__ __launch_bounds__(256) void chamfer_prep_kernel(
    const float* __restrict__ xg, const float* __restrict__ yg,
    half8* __restrict__ Af, half8* __restrict__ Bf, float* __restrict__ rx)
{
    const int p   = blockIdx.x * 256 + threadIdx.x;   // 0..131071
    const int dir = p >> 16;
    const int rem = p & (NSEG - 1);
    const float* __restrict__ R  = dir ? yg : xg;   // row cloud (min FOR its points)
    const float* __restrict__ Cl = dir ? xg : yg;   // col cloud (min OVER its points)

    {   // row side
        const float c0 = R[(size_t)rem * CC + 0];
        const float c1 = R[(size_t)rem * CC + 1];
        const float c2 = R[(size_t)rem * CC + 2];
        const _Float16 h0 = (_Float16)c0, h1 = (_Float16)c1, h2 = (_Float16)c2;
        const float f0 = (float)h0, f1 = (float)h1, f2 = (float)h2;
        rx[p] = fmaf(f0, f0, fmaf(f1, f1, f2 * f2));
        half8 a = { (_Float16)(-2.0f) * h0, (_Float16)(-2.0f) * h1,
                    (_Float16)(-2.0f) * h2, (_Float16)1.0f, (_Float16)1.0f,
                    (_Float16)0.0f, (_Float16)0.0f, (_Float16)0.0f };
        Af[p] = a;
    }
    {   // col side: ry as hi/lo fp16 pair in K-slots 3,4
        const float c0 = Cl[(size_t)rem * CC + 0];
        const float c1 = Cl[(size_t)rem * CC + 1];
        const float c2 = Cl[(size_t)rem * CC + 2];
        const _Float16 h0 = (_Float16)c0, h1 = (_Float16)c1, h2 = (_Float16)c2;
        const float f0 = (float)h0, f1 = (float)h1, f2 = (float)h2;
        const float r  = fmaf(f0, f0, fmaf(f1, f1, f2 * f2));
        const _Float16 hi = (_Float16)r;
        const _Float16 lo = (_Float16)(r - (float)hi);
        half8 bfr = { h0, h1, h2, hi, lo,
                      (_Float16)0.0f, (_Float16)0.0f, (_Float16)0.0f };
        Bf[p] = bfr;
    }
}

// grid = 1024 blocks x 256 thr (4 waves). wave -> (dir, b, rowgroup of 32); full j-range.
__global__ __launch_bounds__(256, 1) void chamfer_min_kernel(
    const half8* __restrict__ Af, const half8* __restrict__ Bf,
    const float* __restrict__ rx, float* __restrict__ bpart)
{
    const int bid  = blockIdx.x;
    const int dir  = bid & 1;
    const int b    = (bid >> 1) & 15;
    const int gq   = bid >> 5;                 // 0..31
    const int tid  = threadIdx.x;
    const int w    = tid >> 6;
    const int lane = tid & 63;
    const int l31  = lane & 31;
    const int hf   = lane >> 5;                // K-half select for A (upper = zeros)
    const int g    = gq * 4 + w;               // rowgroup 0..127

    const size_t base = ((size_t)dir << 16) + ((size_t)b << 12);

    half8 a = {};
    if (hf == 0) a = Af[base + (size_t)g * 32 + l31];   // one-time guarded load

    // per-lane byte address of this block's B stream (lanes 32..63 feed k>=8,
    // which A zeroes out -> content irrelevant but address valid)
    const unsigned long long ba = (unsigned long long)(Bf + base + l31);
    const unsigned alo = (unsigned)ba;
    const unsigned ahi = (unsigned)(ba >> 32);

    float m0  = 3.4e38f, m1  = 3.4e38f, m2  = 3.4e38f, m3  = 3.4e38f;
    float m4  = 3.4e38f, m5  = 3.4e38f, m6  = 3.4e38f, m7  = 3.4e38f;
    float m8  = 3.4e38f, m9  = 3.4e38f, m10 = 3.4e38f, m11 = 3.4e38f;
    float m12 = 3.4e38f, m13 = 3.4e38f, m14 = 3.4e38f, m15 = 3.4e38f;
    int cnt = 16;

    asm volatile(
        // zero-C tile v[64:79], built once, never rewritten
        "v_mov_b32 v64, 0\n\t"  "v_mov_b32 v65, 0\n\t"
        "v_mov_b32 v66, 0\n\t"  "v_mov_b32 v67, 0\n\t"
        "v_mov_b32 v68, 0\n\t"  "v_mov_b32 v69, 0\n\t"
        "v_mov_b32 v70, 0\n\t"  "v_mov_b32 v71, 0\n\t"
        "v_mov_b32 v72, 0\n\t"  "v_mov_b32 v73, 0\n\t"
        "v_mov_b32 v74, 0\n\t"  "v_mov_b32 v75, 0\n\t"
        "v_mov_b32 v76, 0\n\t"  "v_mov_b32 v77, 0\n\t"
        "v_mov_b32 v78, 0\n\t"  "v_mov_b32 v79, 0\n\t"
        // addrP = ba ; addrQ = ba + 2048
        "v_mov_b32 v144, %[alo]\n\t"
        "v_mov_b32 v145, %[ahi]\n\t"
        "v_add_co_u32 v146, vcc, 0x800, v144\n\t"
        "v_addc_co_u32 v147, vcc, 0, v145, vcc\n\t"
        "s_nop 1\n\t"
        // preload P (tiles 0-3) and Q (tiles 4-7)
        "global_load_dwordx4 v[112:115], v[144:145], off\n\t"
        "global_load_dwordx4 v[116:119], v[144:145], off offset:512\n\t"
        "global_load_dwordx4 v[120:123], v[144:145], off offset:1024\n\t"
        "global_load_dwordx4 v[124:127], v[144:145], off offset:1536\n\t"
        "global_load_dwordx4 v[128:131], v[146:147], off\n\t"
        "global_load_dwordx4 v[132:135], v[146:147], off offset:512\n\t"
        "global_load_dwordx4 v[136:139], v[146:147], off offset:1024\n\t"
        "global_load_dwordx4 v[140:143], v[146:147], off offset:1536\n\t"
        "LOOP%=:\n\t"
        PHASE("v[112:115]", "v[116:119]", "v[120:123]", "v[124:127]",
              "v144", "v145", "v[144:145]")
        PHASE("v[128:131]", "v[132:135]", "v[136:139]", "v[140:143]",
              "v146", "v147", "v[146:147]")
        "s_sub_u32 %[cnt], %[cnt], 1\n\t"
        "s_cmp_lg_u32 %[cnt], 0\n\t"
        "s_cbranch_scc1 LOOP%=\n\t"
        "s_waitcnt vmcnt(0)"
        : [m0] "+v"(m0),  [m1] "+v"(m1),  [m2] "+v"(m2),  [m3] "+v"(m3),
          [m4] "+v"(m4),  [m5] "+v"(m5),  [m6] "+v"(m6),  [m7] "+v"(m7),
          [m8] "+v"(m8),  [m9] "+v"(m9),  [m10] "+v"(m10), [m11] "+v"(m11),
          [m12] "+v"(m12), [m13] "+v"(m13), [m14] "+v"(m14), [m15] "+v"(m15),
          [cnt] "+s"(cnt)
        : [fa] "v"(a), [alo] "v"(alo), [ahi] "v"(ahi)
        : "memory", "vcc", "scc",
          "v64","v65","v66","v67","v68","v69","v70","v71",
          "v72","v73","v74","v75","v76","v77","v78","v79",
          "v80","v81","v82","v83","v84","v85","v86","v87",
          "v88","v89","v90","v91","v92","v93","v94","v95",
          "v96","v97","v98","v99","v100","v101","v102","v103",
          "v104","v105","v106","v107","v108","v109","v110","v111",
          "v112","v113","v114","v115","v116","v117","v118","v119",
          "v120","v121","v122","v123","v124","v125","v126","v127",
          "v128","v129","v130","v131","v132","v133","v134","v135",
          "v136","v137","v138","v139","v140","v141","v142","v143",
          "v144","v145","v146","v147");

    float mn[16] = { m0, m1, m2, m3, m4, m5, m6, m7,
                     m8, m9, m10, m11, m12, m13, m14, m15 };

    // cross-lane min over the 32 cols within each half (halves hold different rows)
    #pragma unroll
    for (int s = 0; s < 16; ++s) {
        float v = mn[s];
        v = fminf(v, __shfl_xor(v, 1,  64));
        v = fminf(v, __shfl_xor(v, 2,  64));
        v = fminf(v, __shfl_xor(v, 4,  64));
        v = fminf(v, __shfl_xor(v, 8,  64));
        v = fminf(v, __shfl_xor(v, 16, 64));
        mn[s] = v;
    }

    // add rx per row, sum this half's 16 rows
    const float* __restrict__ rxb = rx + base + (size_t)g * 32;
    float s16 = 0.0f;
    #pragma unroll
    for (int s = 0; s < 16; ++s) {
        const int row = (s & 3) + 8 * (s >> 2) + 4 * hf;  // C/D row map (m101)
        s16 += fmaxf(mn[s] + rxb[row], 0.0f);             // clamp fp noise at 0
    }

    __shared__ float hsum[8];
    if (l31 == 0) hsum[w * 2 + hf] = s16;
    __syncthreads();
    if (tid == 0) {
        float t = 0.0f;
        #pragma unroll
        for (int k = 0; k < 8; ++k) t += hsum[k];
        bpart[bid] = t;            // plain store — no atomics anywhere
    }
}

__global__ __launch_bounds__(256) void chamfer_final_kernel(
    const float* __restrict__ bpart, float* __restrict__ out)
{
    const int tid = threadIdx.x;
    float s = bpart[tid] + bpart[tid + 256] + bpart[tid + 512] + bpart[tid + 768];
    for (int off = 32; off > 0; off >>= 1)
        s += __shfl_down(s, off, 64);
    __shared__ float wsum[4];
    if ((tid & 63) == 0) wsum[tid >> 6] = s;
    __syncthreads();
    if (tid == 0)
        out[0] = (wsum[0] + wsum[1] + wsum[2] + wsum[3]) * (1.0f / NSEG);
}

extern "C" void kernel_launch(void* const* d_in, const int* in_sizes, int n_in,
                              void* d_out, int out_size, void* d_ws, size_t ws_size,
                              hipStream_t stream) {
    const float* x = (const float*)d_in[0];
    const float* y = (const float*)d_in[1];
    float* out = (float*)d_out;

    half8* Af = (half8*)d_ws;
    half8* Bf = (half8*)((char*)d_ws + (size_t)2 * NSEG * sizeof(half8));
    float* rx = (float*)((char*)d_ws + (size_t)4 * NSEG * sizeof(half8));
    float* bpart = (float*)((char*)rx + (size_t)2 * NSEG * sizeof(float));

    chamfer_prep_kernel<<<2 * NSEG / 256, 256, 0, stream>>>(x, y, Af, Bf, rx);
    chamfer_min_kernel<<<NBLK, 256, 0, stream>>>(Af, Bf, rx, bpart);
    chamfer_final_kernel<<<1, 256, 0, stream>>>(bpart, out);
}

// Round 14
// 81.088 us; speedup vs baseline: 1.2226x; 1.0199x over previous
//
#include <hip/hip_runtime.h>
#include <hip/hip_fp16.h>

#define BB 16
#define NN 4096
#define CC 6
#define NSEG (BB * NN)          // 65536 points per direction-role
#define NTILE 128               // 4096 cols / 32
#define NBLK 1024               // min-kernel blocks

using half8  = __attribute__((ext_vector_type(8))) _Float16;

// ---- explicit-register asm inner loop ------------------------------------
// Fixed map (fits under the 128-reg budget of __launch_bounds__(256,4)):
//   zc v[32:47] | d0 v[48:63] | d1 v[64:79]
//   P tiles v[80:83][84:87][88:91][92:95]
//   Q tiles v[96:99][100:103][104:107][108:111]
//   addrP v[112:113]  addrQ v[114:115]
#define FOLD16 \
  "v_min3_f32 %[m0],  %[m0],  v48, v64\n\t" \
  "v_min3_f32 %[m1],  %[m1],  v49, v65\n\t" \
  "v_min3_f32 %[m2],  %[m2],  v50, v66\n\t" \
  "v_min3_f32 %[m3],  %[m3],  v51, v67\n\t" \
  "v_min3_f32 %[m4],  %[m4],  v52, v68\n\t" \
  "v_min3_f32 %[m5],  %[m5],  v53, v69\n\t" \
  "v_min3_f32 %[m6],  %[m6],  v54, v70\n\t" \
  "v_min3_f32 %[m7],  %[m7],  v55, v71\n\t" \
  "v_min3_f32 %[m8],  %[m8],  v56, v72\n\t" \
  "v_min3_f32 %[m9],  %[m9],  v57, v73\n\t" \
  "v_min3_f32 %[m10], %[m10], v58, v74\n\t" \
  "v_min3_f32 %[m11], %[m11], v59, v75\n\t" \
  "v_min3_f32 %[m12], %[m12], v60, v76\n\t" \
  "v_min3_f32 %[m13], %[m13], v61, v77\n\t" \
  "v_min3_f32 %[m14], %[m14], v62, v78\n\t" \
  "v_min3_f32 %[m15], %[m15], v63, v79\n\t"

#define PHASE(T0, T1, T2, T3, ALO, AHI, APAIR)                              \
  "s_waitcnt vmcnt(4)\n\t"                                                  \
  "v_mfma_f32_32x32x16_f16 v[48:63], %[fa], " T0 ", v[32:47]\n\t"           \
  "v_mfma_f32_32x32x16_f16 v[64:79], %[fa], " T1 ", v[32:47]\n\t"           \
  "v_add_co_u32 " ALO ", vcc, 0x1000, " ALO "\n\t"                          \
  "v_addc_co_u32 " AHI ", vcc, 0, " AHI ", vcc\n\t"                         \
  "s_nop 1\n\t"                                                             \
  "global_load_dwordx4 " T0 ", " APAIR ", off\n\t"                          \
  "global_load_dwordx4 " T1 ", " APAIR ", off offset:512\n\t"               \
  "s_nop 7\n\t"                                                             \
  "s_nop 7\n\t"                                                             \
  FOLD16                                                                    \
  "v_mfma_f32_32x32x16_f16 v[48:63], %[fa], " T2 ", v[32:47]\n\t"           \
  "v_mfma_f32_32x32x16_f16 v[64:79], %[fa], " T3 ", v[32:47]\n\t"           \
  "global_load_dwordx4 " T2 ", " APAIR ", off offset:1024\n\t"              \
  "global_load_dwordx4 " T3 ", " APAIR ", off offset:1536\n\t"              \
  "s_nop 7\n\t"                                                             \
  "s_nop 7\n\t"                                                             \
  "s_nop 4\n\t"                                                             \
  FOLD16

// ws layout:
//   half8 Af[2][BB][NN] @ 0     (2 MB) A entry per ROW point: (-2h0,-2h1,-2h2,1,1,0,0,0)
//   half8 Bf[2][BB][NN] @ 2 MB  (2 MB) B entry per COL point: ( h0, h1, h2,hi,lo,0,0,0)
//   float rx[2][BB][NN] @ 4 MB  (512 KB) row-point |h|^2 fp32 (absorbs tail over-read)
//   float bpart[NBLK]   @ 4.5MB (4 KB) per-block partials

__global__ __launch_bounds__(256) void chamfer_prep_kernel(
    const float* __restrict__ xg, const float* __restrict__ yg,
    half8* __restrict__ Af, half8* __restrict__ Bf, float* __restrict__ rx)
{
    const int p   = blockIdx.x * 256 + threadIdx.x;   // 0..131071
    const int dir = p >> 16;
    const int rem = p & (NSEG - 1);
    const float* __restrict__ R  = dir ? yg : xg;   // row cloud (min FOR its points)
    const float* __restrict__ Cl = dir ? xg : yg;   // col cloud (min OVER its points)

    {   // row side
        const float c0 = R[(size_t)rem * CC + 0];
        const float c1 = R[(size_t)rem * CC + 1];
        const float c2 = R[(size_t)rem * CC + 2];
        const _Float16 h0 = (_Float16)c0, h1 = (_Float16)c1, h2 = (_Float16)c2;
        const float f0 = (float)h0, f1 = (float)h1, f2 = (float)h2;
        rx[p] = fmaf(f0, f0, fmaf(f1, f1, f2 * f2));
        half8 a = { (_Float16)(-2.0f) * h0, (_Float16)(-2.0f) * h1,
                    (_Float16)(-2.0f) * h2, (_Float16)1.0f, (_Float16)1.0f,
                    (_Float16)0.0f, (_Float16)0.0f, (_Float16)0.0f };
        Af[p] = a;
    }
    {   // col side: ry as hi/lo fp16 pair in K-slots 3,4
        const float c0 = Cl[(size_t)rem * CC + 0];
        const float c1 = Cl[(size_t)rem * CC + 1];
        const float c2 = Cl[(size_t)rem * CC + 2];
        const _Float16 h0 = (_Float16)c0, h1 = (_Float16)c1, h2 = (_Float16)c2;
        const float f0 = (float)h0, f1 = (float)h1, f2 = (float)h2;
        const float r  = fmaf(f0, f0, fmaf(f1, f1, f2 * f2));
        const _Float16 hi = (_Float16)r;
        const _Float16 lo = (_Float16)(r - (float)hi);
        half8 bfr = { h0, h1, h2, hi, lo,
                      (_Float16)0.0f, (_Float16)0.0f, (_Float16)0.0f };
        Bf[p] = bfr;
    }
}

// grid = 1024 blocks x 256 thr (4 waves). wave -> (dir, b, rowgroup of 32); full j-range.
// Fixed asm map tops out at v115; compiler operands fit below v32 / above v115,
// so VGPR_Count <= 128 and __launch_bounds__(256,4) gives 4 waves/SIMD, no tail.
__global__ __launch_bounds__(256, 4) void chamfer_min_kernel(
    const half8* __restrict__ Af, const half8* __restrict__ Bf,
    const float* __restrict__ rx, float* __restrict__ bpart)
{
    const int bid  = blockIdx.x;
    const int dir  = bid & 1;
    const int b    = (bid >> 1) & 15;
    const int gq   = bid >> 5;                 // 0..31
    const int tid  = threadIdx.x;
    const int w    = tid >> 6;
    const int lane = tid & 63;
    const int l31  = lane & 31;
    const int hf   = lane >> 5;                // K-half select for A (upper = zeros)
    const int g    = gq * 4 + w;               // rowgroup 0..127

    const size_t base = ((size_t)dir << 16) + ((size_t)b << 12);

    half8 a = {};
    if (hf == 0) a = Af[base + (size_t)g * 32 + l31];   // one-time guarded load

    // per-lane byte address of this block's B stream (lanes 32..63 feed k>=8,
    // which A zeroes out -> content irrelevant but address valid)
    const unsigned long long ba = (unsigned long long)(Bf + base + l31);
    const unsigned alo = (unsigned)ba;
    const unsigned ahi = (unsigned)(ba >> 32);

    float m0  = 3.4e38f, m1  = 3.4e38f, m2  = 3.4e38f, m3  = 3.4e38f;
    float m4  = 3.4e38f, m5  = 3.4e38f, m6  = 3.4e38f, m7  = 3.4e38f;
    float m8  = 3.4e38f, m9  = 3.4e38f, m10 = 3.4e38f, m11 = 3.4e38f;
    float m12 = 3.4e38f, m13 = 3.4e38f, m14 = 3.4e38f, m15 = 3.4e38f;
    int cnt = 16;

    asm volatile(
        // zero-C tile v[32:47], built once, never rewritten
        "v_mov_b32 v32, 0\n\t"  "v_mov_b32 v33, 0\n\t"
        "v_mov_b32 v34, 0\n\t"  "v_mov_b32 v35, 0\n\t"
        "v_mov_b32 v36, 0\n\t"  "v_mov_b32 v37, 0\n\t"
        "v_mov_b32 v38, 0\n\t"  "v_mov_b32 v39, 0\n\t"
        "v_mov_b32 v40, 0\n\t"  "v_mov_b32 v41, 0\n\t"
        "v_mov_b32 v42, 0\n\t"  "v_mov_b32 v43, 0\n\t"
        "v_mov_b32 v44, 0\n\t"  "v_mov_b32 v45, 0\n\t"
        "v_mov_b32 v46, 0\n\t"  "v_mov_b32 v47, 0\n\t"
        // addrP = ba ; addrQ = ba + 2048
        "v_mov_b32 v112, %[alo]\n\t"
        "v_mov_b32 v113, %[ahi]\n\t"
        "v_add_co_u32 v114, vcc, 0x800, v112\n\t"
        "v_addc_co_u32 v115, vcc, 0, v113, vcc\n\t"
        "s_nop 1\n\t"
        // preload P (tiles 0-3) and Q (tiles 4-7)
        "global_load_dwordx4 v[80:83],   v[112:113], off\n\t"
        "global_load_dwordx4 v[84:87],   v[112:113], off offset:512\n\t"
        "global_load_dwordx4 v[88:91],   v[112:113], off offset:1024\n\t"
        "global_load_dwordx4 v[92:95],   v[112:113], off offset:1536\n\t"
        "global_load_dwordx4 v[96:99],   v[114:115], off\n\t"
        "global_load_dwordx4 v[100:103], v[114:115], off offset:512\n\t"
        "global_load_dwordx4 v[104:107], v[114:115], off offset:1024\n\t"
        "global_load_dwordx4 v[108:111], v[114:115], off offset:1536\n\t"
        "LOOP%=:\n\t"
        PHASE("v[80:83]", "v[84:87]", "v[88:91]", "v[92:95]",
              "v112", "v113", "v[112:113]")
        PHASE("v[96:99]", "v[100:103]", "v[104:107]", "v[108:111]",
              "v114", "v115", "v[114:115]")
        "s_sub_u32 %[cnt], %[cnt], 1\n\t"
        "s_cmp_lg_u32 %[cnt], 0\n\t"
        "s_cbranch_scc1 LOOP%=\n\t"
        "s_waitcnt vmcnt(0)"
        : [m0] "+v"(m0),  [m1] "+v"(m1),  [m2] "+v"(m2),  [m3] "+v"(m3),
          [m4] "+v"(m4),  [m5] "+v"(m5),  [m6] "+v"(m6),  [m7] "+v"(m7),
          [m8] "+v"(m8),  [m9] "+v"(m9),  [m10] "+v"(m10), [m11] "+v"(m11),
          [m12] "+v"(m12), [m13] "+v"(m13), [m14] "+v"(m14), [m15] "+v"(m15),
          [cnt] "+s"(cnt)
        : [fa] "v"(a), [alo] "v"(alo), [ahi] "v"(ahi)
        : "memory", "vcc", "scc",
          "v32","v33","v34","v35","v36","v37","v38","v39",
          "v40","v41","v42","v43","v44","v45","v46","v47",
          "v48","v49","v50","v51","v52","v53","v54","v55",
          "v56","v57","v58","v59","v60","v61","v62","v63",
          "v64","v65","v66","v67","v68","v69","v70","v71",
          "v72","v73","v74","v75","v76","v77","v78","v79",
          "v80","v81","v82","v83","v84","v85","v86","v87",
          "v88","v89","v90","v91","v92","v93","v94","v95",
          "v96","v97","v98","v99","v100","v101","v102","v103",
          "v104","v105","v106","v107","v108","v109","v110","v111",
          "v112","v113","v114","v115");

    float mn[16] = { m0, m1, m2, m3, m4, m5, m6, m7,
                     m8, m9, m10, m11, m12, m13, m14, m15 };

    // cross-lane min over the 32 cols within each half (halves hold different rows)
    #pragma unroll
    for (int s = 0; s < 16; ++s) {
        float v = mn[s];
        v = fminf(v, __shfl_xor(v, 1,  64));
        v = fminf(v, __shfl_xor(v, 2,  64));
        v = fminf(v, __shfl_xor(v, 4,  64));
        v = fminf(v, __shfl_xor(v, 8,  64));
        v = fminf(v, __shfl_xor(v, 16, 64));
        mn[s] = v;
    }

    // add rx per row, sum this half's 16 rows
    const float* __restrict__ rxb = rx + base + (size_t)g * 32;
    float s16 = 0.0f;
    #pragma unroll
    for (int s = 0; s < 16; ++s) {
        const int row = (s & 3) + 8 * (s >> 2) + 4 * hf;  // C/D row map (m101)
        s16 += fmaxf(mn[s] + rxb[row], 0.0f);             // clamp fp noise at 0
    }

    __shared__ float hsum[8];
    if (l31 == 0) hsum[w * 2 + hf] = s16;
    __syncthreads();
    if (tid == 0) {
        float t = 0.0f;
        #pragma unroll
        for (int k = 0; k < 8; ++k) t += hsum[k];
        bpart[bid] = t;            // plain store — no atomics anywhere
    }
}

__global__ __launch_bounds__(256) void chamfer_final_kernel(
    const float* __restrict__ bpart, float* __restrict__ out)
{
    const int tid = threadIdx.x;
    float s = bpart[tid] + bpart[tid + 256] + bpart[tid + 512] + bpart[tid + 768];
    for (int off = 32; off > 0; off >>= 1)
        s += __shfl_down(s, off, 64);
    __shared__ float wsum[4];
    if ((tid & 63) == 0) wsum[tid >> 6] = s;
    __syncthreads();
    if (tid == 0)
        out[0] = (wsum[0] + wsum[1] + wsum[2] + wsum[3]) * (1.0f / NSEG);
}

extern "C" void kernel_launch(void* const* d_in, const int* in_sizes, int n_in,
                              void* d_out, int out_size, void* d_ws, size_t ws_size,
                              hipStream_t stream) {
    const float* x = (const float*)d_in[0];
    const float* y = (const float*)d_in[1];
    float* out = (float*)d_out;

    half8* Af = (half8*)d_ws;
    half8* Bf = (half8*)((char*)d_ws + (size_t)2 * NSEG * sizeof(half8));
    float* rx = (float*)((char*)d_ws + (size_t)4 * NSEG * sizeof(half8));
    float* bpart = (float*)((char*)rx + (size_t)2 * NSEG * sizeof(float));

    chamfer_prep_kernel<<<2 * NSEG / 256, 256, 0, stream>>>(x, y, Af, Bf, rx);
    chamfer_min_kernel<<<NBLK, 256, 0, stream>>>(Af, Bf, rx, bpart);
    chamfer_final_kernel<<<1, 256, 0, stream>>>(bpart, out);
}